// Round 3
// baseline (71.408 us; speedup 1.0000x reference)
//
#include <hip/hip_runtime.h>

// DerivativeNet: masked 1-D radius-1 stencil along last axis.
// u: (8,4,1024,1024) f32; nmask: (1,1,1024,1024) f32 broadcast over 32 batch
// rows. Mask row y = r & 1023 is shared by 32 u-rows -> hoist indicators.
//
// Structure (R3): one block per (mask row, half-batch). Load phase issues all
// 16 rows' fragments (48 VMEM instrs/wave in flight = max MLP), then compute +
// nontemporal store. Fill kernel hits 7 TB/s at 10% occupancy -> BW comes from
// outstanding requests, not occupancy.
//
// Numerics: exact reference expression order (R1 form, absmax was 0.0);
// indicators er/e1/e2 are exact on {0,1} mask values.

#define W 1024
#define RPB 16             // batch rows per block
#define HINV 100.0f        // 1/h
#define HINV2 50.0f        // 1/(2h)

typedef float f32x4 __attribute__((ext_vector_type(4)));

__global__ __launch_bounds__(256)
void deriv_kernel(const float* __restrict__ u,
                  const float* __restrict__ nmask,
                  float* __restrict__ out) {
    const int b = blockIdx.x;
    const int y = b >> 1;                  // mask row 0..1023
    const int k0 = (b & 1) * RPB;          // batch-row start (0 or 16)
    const int x = threadIdx.x * 4;         // 4 contiguous elements per thread

    const bool le = (x == 0);
    const bool re = (x + 4 >= W);
    const int xm = le ? 0 : x - 1;         // clamped halo addresses (no OOB,
    const int xp = re ? W - 1 : x + 4;     // no divergent exec-masked loads)

    // ---- mask -> indicator registers (once per block) ----
    const float* mrow = nmask + (size_t)y * W;
    const f32x4 mc = *(const f32x4*)(mrow + x);
    float m_m1 = mrow[xm]; m_m1 = le ? 0.0f : m_m1;
    float m_p4 = mrow[xp]; m_p4 = re ? 0.0f : m_p4;
    const float mv[6] = { m_m1, mc[0], mc[1], mc[2], mc[3], m_p4 };

    float er[4], e1[4], e2[4];
    #pragma unroll
    for (int j = 0; j < 4; ++j) {
        er[j] = (mv[j] + mv[j+1] + mv[j+2] == 3.0f) ? 1.0f : 0.0f;
        e1[j] = (mv[j+1] - mv[j]   ==  1.0f) ? 1.0f : 0.0f;
        e2[j] = (mv[j+2] - mv[j+1] == -1.0f) ? 1.0f : 0.0f;
    }

    const size_t kstride = (size_t)W * W;              // 4 MiB between batches
    const size_t base = ((size_t)k0 * W + y) * W;

    // ---- load phase: all 16 rows' fragments in flight ----
    f32x4 uc[RPB]; float um[RPB], up[RPB];
    #pragma unroll
    for (int k = 0; k < RPB; ++k) {
        const float* urow = u + base + (size_t)k * kstride;
        uc[k] = *(const f32x4*)(urow + x);
        um[k] = urow[xm];
        up[k] = urow[xp];
    }

    // ---- compute + store phase ----
    #pragma unroll
    for (int k = 0; k < RPB; ++k) {
        const float um1 = le ? 0.0f : um[k];
        const float up4 = re ? 0.0f : up[k];
        const float uv[6] = { um1, uc[k][0], uc[k][1], uc[k][2], uc[k][3], up4 };

        f32x4 o;
        #pragma unroll
        for (int j = 0; j < 4; ++j) {
            const float internal_d = (uv[j+2] - uv[j])   * HINV2;
            const float left_d     = (uv[j+2] - uv[j+1]) * HINV;
            const float right_d    = (uv[j+1] - uv[j])   * HINV;
            o[j] = er[j] * internal_d + e1[j] * left_d + e2[j] * right_d;
        }
        __builtin_nontemporal_store(o, (f32x4*)(out + base + (size_t)k * kstride + x));
    }
}

extern "C" void kernel_launch(void* const* d_in, const int* in_sizes, int n_in,
                              void* d_out, int out_size, void* d_ws, size_t ws_size,
                              hipStream_t stream) {
    const float* u = (const float*)d_in[0];
    const float* nmask = (const float*)d_in[1];
    float* out = (float*)d_out;

    const int rows = in_sizes[0] / W;            // 32768
    const int blocks = rows / RPB;               // 2048
    deriv_kernel<<<blocks, 256, 0, stream>>>(u, nmask, out);
}

// Round 4
// 43.404 us; speedup vs baseline: 1.6452x; 1.6452x over previous
//
#include <hip/hip_runtime.h>

// DerivativeNet: masked radius-1 stencil along last axis (h = 0.01).
// u: (8,4,1024,1024) f32; nmask: (1,1,1024,1024) f32 broadcast over 32 batch
// rows (mask row = r & 1023) -> indicators hoisted once per block.
//
// R4: halo values via intra-wave shuffle instead of wave-wide scalar loads.
//   u[x-1] = lane-1's uc.w, u[x+4] = lane+1's uc.x; only wave-boundary lanes
//   (2 of 64) do a divergent scalar load. Cuts read-issue per row from
//   3 wave-VMEM instrs to ~1. Demand-byte model: R2 ran at 5.2 TB/s of the
//   6.3 TB/s copy ceiling; extra VMEM issue is the stencil-vs-copy gap.
// Numerics: exact reference expression order (R3 form, absmax 0.0).

#define W 1024
#define RPB 16             // batch rows per block
#define HINV 100.0f        // 1/h
#define HINV2 50.0f        // 1/(2h)

typedef float f32x4 __attribute__((ext_vector_type(4)));

__global__ __launch_bounds__(256)
void deriv_kernel(const float* __restrict__ u,
                  const float* __restrict__ nmask,
                  float* __restrict__ out) {
    const int b = blockIdx.x;
    const int y = b >> 1;                  // mask row 0..1023
    const int k0 = (b & 1) * RPB;          // batch-row start (0 or 16)
    const int tid = threadIdx.x;
    const int x = tid * 4;                 // 4 contiguous elements per thread
    const int lane = tid & 63;

    const bool le = (tid == 0);            // x == 0 (true array edge)
    const bool re = (tid == 255);          // x+4 == W (true array edge)
    const bool need_lo = (lane == 0) && !le;    // wave boundary, interior
    const bool need_hi = (lane == 63) && !re;

    // ---- mask -> indicator registers (once per block; clamped halo loads) ----
    const int xm = le ? 0 : x - 1;
    const int xp = re ? W - 1 : x + 4;
    const float* mrow = nmask + (size_t)y * W;
    const f32x4 mc = *(const f32x4*)(mrow + x);
    float m_m1 = mrow[xm]; m_m1 = le ? 0.0f : m_m1;
    float m_p4 = mrow[xp]; m_p4 = re ? 0.0f : m_p4;
    const float mv[6] = { m_m1, mc[0], mc[1], mc[2], mc[3], m_p4 };

    float er[4], e1[4], e2[4];
    #pragma unroll
    for (int j = 0; j < 4; ++j) {
        er[j] = (mv[j] + mv[j+1] + mv[j+2] == 3.0f) ? 1.0f : 0.0f;
        e1[j] = (mv[j+1] - mv[j]   ==  1.0f) ? 1.0f : 0.0f;
        e2[j] = (mv[j+2] - mv[j+1] == -1.0f) ? 1.0f : 0.0f;
    }

    const size_t kstride = (size_t)W * W;          // 4 MiB between batch rows
    const size_t rowbase0 = ((size_t)k0 * W + y) * W;

    #pragma unroll 4
    for (int k = 0; k < RPB; ++k) {
        const float* urow = u + rowbase0 + (size_t)k * kstride;

        const f32x4 uc = *(const f32x4*)(urow + x);

        // wave-boundary halos: divergent 2-lane loads only
        float lo = 0.0f, hi = 0.0f;
        if (need_lo) lo = urow[x - 1];
        if (need_hi) hi = urow[x + 4];

        // interior halos from neighboring lanes' registers
        float um1 = __shfl_up(uc[3], 1);           // lane-1's u[x-1]
        um1 = (lane == 0) ? lo : um1;              // tid0: lo==0 (true edge)
        float up4 = __shfl_down(uc[0], 1);         // lane+1's u[x+4]
        up4 = (lane == 63) ? hi : up4;             // tid255: hi==0 (true edge)

        const float uv[6] = { um1, uc[0], uc[1], uc[2], uc[3], up4 };

        f32x4 o;
        #pragma unroll
        for (int j = 0; j < 4; ++j) {
            const float internal_d = (uv[j+2] - uv[j])   * HINV2;
            const float left_d     = (uv[j+2] - uv[j+1]) * HINV;
            const float right_d    = (uv[j+1] - uv[j])   * HINV;
            o[j] = er[j] * internal_d + e1[j] * left_d + e2[j] * right_d;
        }
        __builtin_nontemporal_store(o, (f32x4*)(out + rowbase0 + (size_t)k * kstride + x));
    }
}

extern "C" void kernel_launch(void* const* d_in, const int* in_sizes, int n_in,
                              void* d_out, int out_size, void* d_ws, size_t ws_size,
                              hipStream_t stream) {
    const float* u = (const float*)d_in[0];
    const float* nmask = (const float*)d_in[1];
    float* out = (float*)d_out;

    const int rows = in_sizes[0] / W;            // 32768
    const int blocks = rows / RPB;               // 2048
    deriv_kernel<<<blocks, 256, 0, stream>>>(u, nmask, out);
}